// Round 2
// baseline (490.384 us; speedup 1.0000x reference)
//
#include <hip/hip_runtime.h>

// HyperConnections fused kernel, MI355X (gfx950). ALL I/O float32 (per reference).
// Shapes: h (8192, 4, 2048), h_o (8192, 2048), out (8192, 4, 2048).
// One 256-thread block per (b,l) position; each thread owns 8 contiguous
// d-elements (2x float4 per row). h kept in registers across all stages so it
// is read from HBM exactly once. HBM-bound: ~604 MB/dispatch -> ~96 us floor.

#define NDIM   2048
#define NRATE  4
#define DSCALE 0.01f
#define LEPS   1e-5f

__global__ __launch_bounds__(256) void hc_fused(
    const float* __restrict__ h,     // (P, 4, 2048)
    const float* __restrict__ h_o,   // (P, 2048)
    const float* __restrict__ g_,    // (2048) ln_gamma
    const float* __restrict__ b_,    // (2048) ln_beta
    const float* __restrict__ Afn,   // (2048, 5) dynamic_alpha_fn
    const float* __restrict__ Bfn,   // (2048)    dynamic_beta_fn
    const float* __restrict__ sA,    // (4, 5)    static_alpha
    const float* __restrict__ sB,    // (4)       static_beta
    float* __restrict__ out)         // (P, 4, 2048)
{
    __shared__ float s_red[4][20];
    __shared__ float s_bc[20];

    const int t    = threadIdx.x;
    const int lane = t & 63;
    const int wave = t >> 6;
    const size_t pbase = (size_t)blockIdx.x * (NRATE * NDIM);
    const int dbase = t * 8;   // this thread's first d index

    // ---- stage 1: load h rows (kept in registers), per-thread sum/sumsq ----
    float hv[NRATE][8];
    float vals[8];
    #pragma unroll
    for (int n = 0; n < NRATE; n++) {
        const float4 r0 = *(const float4*)(h + pbase + n * NDIM + dbase);
        const float4 r1 = *(const float4*)(h + pbase + n * NDIM + dbase + 4);
        hv[n][0] = r0.x; hv[n][1] = r0.y; hv[n][2] = r0.z; hv[n][3] = r0.w;
        hv[n][4] = r1.x; hv[n][5] = r1.y; hv[n][6] = r1.z; hv[n][7] = r1.w;
        float s = 0.f, ss = 0.f;
        #pragma unroll
        for (int i = 0; i < 8; i++) { s += hv[n][i]; ss = fmaf(hv[n][i], hv[n][i], ss); }
        vals[2 * n]     = s;
        vals[2 * n + 1] = ss;
    }
    #pragma unroll
    for (int i = 0; i < 8; i++) {
        float v = vals[i];
        #pragma unroll
        for (int off = 32; off; off >>= 1) v += __shfl_down(v, off, 64);
        if (lane == 0) s_red[wave][i] = v;
    }
    __syncthreads();
    if (t < 8) s_bc[t] = s_red[0][t] + s_red[1][t] + s_red[2][t] + s_red[3][t];
    __syncthreads();

    float mean[NRATE], rstd[NRATE];
    #pragma unroll
    for (int n = 0; n < NRATE; n++) {
        float m   = s_bc[2 * n] * (1.0f / NDIM);
        float var = s_bc[2 * n + 1] * (1.0f / NDIM) - m * m;
        mean[n] = m;
        rstd[n] = rsqrtf(var + LEPS);
    }

    // ---- stage 2: partials for dyn_alpha cols 1..4 (col 0 is dropped by the
    //      reference's [..., 1:, :]) and dyn_beta ----
    float pav[20];
    #pragma unroll
    for (int i = 0; i < 20; i++) pav[i] = 0.f;
    #pragma unroll
    for (int i = 0; i < 8; i++) {
        const int d = dbase + i;
        const float gvi  = g_[d];
        const float bvi  = b_[d];
        const float dbvi = Bfn[d];
        const float a0 = Afn[d * 5 + 1];
        const float a1 = Afn[d * 5 + 2];
        const float a2 = Afn[d * 5 + 3];
        const float a3 = Afn[d * 5 + 4];
        #pragma unroll
        for (int n = 0; n < NRATE; n++) {
            const float nh = fmaf((hv[n][i] - mean[n]) * rstd[n], gvi, bvi);
            pav[n * 4 + 0] = fmaf(nh, a0, pav[n * 4 + 0]);
            pav[n * 4 + 1] = fmaf(nh, a1, pav[n * 4 + 1]);
            pav[n * 4 + 2] = fmaf(nh, a2, pav[n * 4 + 2]);
            pav[n * 4 + 3] = fmaf(nh, a3, pav[n * 4 + 3]);
            pav[16 + n]    = fmaf(nh, dbvi, pav[16 + n]);
        }
    }
    #pragma unroll
    for (int i = 0; i < 20; i++) {
        float v = pav[i];
        #pragma unroll
        for (int off = 32; off; off >>= 1) v += __shfl_down(v, off, 64);
        if (lane == 0) s_red[wave][i] = v;
    }
    __syncthreads();
    if (t < 20) s_bc[t] = s_red[0][t] + s_red[1][t] + s_red[2][t] + s_red[3][t];
    __syncthreads();

    // ---- stage 3: finalize alpha (cols 1..4) and beta ----
    float alpha_f[NRATE][4], beta_f[NRATE];
    #pragma unroll
    for (int n = 0; n < NRATE; n++) {
        #pragma unroll
        for (int k = 0; k < 4; k++)
            alpha_f[n][k] = fmaf(DSCALE, s_bc[n * 4 + k], sA[n * 5 + 1 + k]);
        beta_f[n] = fmaf(DSCALE, s_bc[16 + n], sB[n]);
    }

    // ---- stage 4: out[j,d] = h_o[d]*beta[j] + sum_n alpha[n][j+1]*h[n,d] ----
    const float4 ro0 = *(const float4*)(h_o + (size_t)blockIdx.x * NDIM + dbase);
    const float4 ro1 = *(const float4*)(h_o + (size_t)blockIdx.x * NDIM + dbase + 4);
    float ho[8];
    ho[0] = ro0.x; ho[1] = ro0.y; ho[2] = ro0.z; ho[3] = ro0.w;
    ho[4] = ro1.x; ho[5] = ro1.y; ho[6] = ro1.z; ho[7] = ro1.w;

    #pragma unroll
    for (int j = 0; j < NRATE; j++) {
        float o[8];
        #pragma unroll
        for (int i = 0; i < 8; i++) {
            float acc = ho[i] * beta_f[j];
            #pragma unroll
            for (int n = 0; n < NRATE; n++) acc = fmaf(alpha_f[n][j], hv[n][i], acc);
            o[i] = acc;
        }
        float4 w0 = make_float4(o[0], o[1], o[2], o[3]);
        float4 w1 = make_float4(o[4], o[5], o[6], o[7]);
        *(float4*)(out + pbase + j * NDIM + dbase)     = w0;
        *(float4*)(out + pbase + j * NDIM + dbase + 4) = w1;
    }
}

extern "C" void kernel_launch(void* const* d_in, const int* in_sizes, int n_in,
                              void* d_out, int out_size, void* d_ws, size_t ws_size,
                              hipStream_t stream) {
    const float* h   = (const float*)d_in[0];
    const float* h_o = (const float*)d_in[1];
    const float* g   = (const float*)d_in[2];
    const float* b   = (const float*)d_in[3];
    const float* A   = (const float*)d_in[4];
    const float* Bf  = (const float*)d_in[5];
    const float* sA  = (const float*)d_in[6];
    const float* sB  = (const float*)d_in[7];
    float* out = (float*)d_out;

    const int P = in_sizes[1] / NDIM;   // b*l = 8192
    hc_fused<<<P, 256, 0, stream>>>(h, h_o, g, b, A, Bf, sA, sB, out);
}